// Round 4
// baseline (266.442 us; speedup 1.0000x reference)
//
#include <hip/hip_runtime.h>
#include <hip/hip_bf16.h>
#include <stdint.h>
#include <string.h>

// B=2, S=2048, D_MODEL=1024, H=16, Dh=64
#define SEQ   2048
#define DM    1024
#define NH    16
#define NB    2

typedef __attribute__((ext_vector_type(8))) short bf16x8;
typedef __attribute__((ext_vector_type(4))) float f32x4;
typedef unsigned short u16;
typedef unsigned int   u32;

__device__ __forceinline__ u16 f2bf(float f) {
    u32 u = __float_as_uint(f);
    u += 0x7FFF + ((u >> 16) & 1);   // RNE
    return (u16)(u >> 16);
}
__device__ __forceinline__ u32 pk2bf(float a, float b) {
    __hip_bfloat162 p = __float22bfloat162_rn(make_float2(a, b));
    u32 u; memcpy(&u, &p, 4); return u;
}
__device__ __forceinline__ float fexp2(float x) {
#if __has_builtin(__builtin_amdgcn_exp2f)
    return __builtin_amdgcn_exp2f(x);
#else
    return exp2f(x);
#endif
}
// exp2 with mask folded in: keep-bit (from inverted mask word) sign-extended
// and ANDed into the result. masked -> exactly 0.0f (== exp2(-1e9) path).
__device__ __forceinline__ float mask_exp2(float s, u32 lsel, int pos) {
#if __has_builtin(__builtin_amdgcn_sbfe)
    u32 keep = (u32)__builtin_amdgcn_sbfe((int)lsel, pos, 1);
#else
    u32 keep = (u32)((int)(lsel << (31 - pos)) >> 31);
#endif
    return __uint_as_float(__float_as_uint(fexp2(s)) & keep);
}
// async global->LDS, 16B/lane; LDS dest = wave-uniform base + lane*16
__device__ __forceinline__ void gl_lds16(const void* g, void* l) {
    __builtin_amdgcn_global_load_lds(
        (const __attribute__((address_space(1))) u32*)g,
        (__attribute__((address_space(3))) u32*)l, 16, 0, 0);
}
// Raw barrier WITHOUT vmcnt(0) drain: wait until only N newest VMEM ops
// remain in flight, then s_barrier. "memory" clobber pins ordering.
__device__ __forceinline__ void wbar_vm3() { asm volatile("s_waitcnt vmcnt(3)\ns_barrier" ::: "memory"); }
__device__ __forceinline__ void wbar_vm4() { asm volatile("s_waitcnt vmcnt(4)\ns_barrier" ::: "memory"); }
__device__ __forceinline__ void vm_drain() { asm volatile("s_waitcnt vmcnt(0)" ::: "memory"); }

// ---------------------------------------------------------------------------
// fp32 -> bf16 bulk convert; Wq pre-scaled by 0.125*log2(e) (exp2 domain).
// ---------------------------------------------------------------------------
struct CvtArgs {
    const float* s[7];
    u16* d[7];
    float scale[7];
    int start[8];
};
__global__ __launch_bounds__(256) void cvt_kernel(CvtArgs a) {
    int bid = blockIdx.x;
    int seg = 0;
#pragma unroll
    for (int i = 1; i < 7; ++i) if (bid >= a.start[i]) seg = i;
    float sc = a.scale[seg];
    size_t base = (size_t)(bid - a.start[seg]) * 2048 + threadIdx.x * 8;
    const float4* s4 = (const float4*)(a.s[seg] + base);
    float4 x = s4[0], y = s4[1];
    u32 r[4];
    r[0] = pk2bf(x.x*sc, x.y*sc); r[1] = pk2bf(x.z*sc, x.w*sc);
    r[2] = pk2bf(y.x*sc, y.y*sc); r[3] = pk2bf(y.z*sc, y.w*sc);
    *(uint4*)(a.d[seg] + base) = *(uint4*)r;
}

// ---------------------------------------------------------------------------
// mask -> bits; word = bits[(b*2048+m)*64 + n/32]
// ---------------------------------------------------------------------------
__global__ void maskpack_kernel(const int* __restrict__ mask,
                                unsigned int* __restrict__ bits) {
    int gid = blockIdx.x * 256 + threadIdx.x;
    int m = mask[gid];
    unsigned long long bal = __ballot(m != 0);
    int lane = threadIdx.x & 63;
    if (lane == 0)       bits[gid >> 5] = (u32)(bal & 0xFFFFFFFFull);
    else if (lane == 32) bits[gid >> 5] = (u32)(bal >> 32);
}

// ---------------------------------------------------------------------------
// bf16 GEMM: Y[r][c] = sum_k A[r][k]*B[c][k], K=1024, BK=32.
// Triple-buffered LDS, prefetch distance 2, raw-barrier pipeline (no vmcnt(0)
// drains inside the loop). XOR swizzle (4 chunks/row) for conflict-free b128.
// RT=4: 128x128 tile; RT=2: 64x128. 256 threads, waves 2x2.
// mode 0: bf16 (B,H,S,64); mode 1: bf16 (B,H,64,S); mode 2: fp32 row-major.
// ---------------------------------------------------------------------------
template<int RT>
__device__ __forceinline__ void gemm_body(const u16* __restrict__ A,
                                          const u16* __restrict__ Bm,
                                          void* __restrict__ Y,
                                          int rtile, int ctile, int mode,
                                          u16* sA, u16* sB) {
    constexpr int ABUF = RT * 32 * 32;          // u16 per A buffer
    constexpr int BBUF = 128 * 32;
    const int tid  = threadIdx.x;
    const int wv   = tid >> 6, lane = tid & 63;
    const int quad = lane >> 4, ln = lane & 15;
    const int wr   = wv >> 1,  wc  = wv & 1;

    const int lr4 = lane >> 2;                          // row in 16-row shot
    const int lcc = ((lane & 3) ^ ((lane >> 3) & 3)) * 8;  // swizzled src col

    const u16* gA[RT/2]; u16* lA[RT/2];
#pragma unroll
    for (int s = 0; s < RT/2; ++s) {
        int seg = wv * (RT/2) + s;
        gA[s] = A + (size_t)(rtile * (RT*32) + seg*16 + lr4) * 1024 + lcc;
        lA[s] = sA + seg * 512;
    }
    const u16* gB[2]; u16* lB[2];
#pragma unroll
    for (int s = 0; s < 2; ++s) {
        int seg = wv * 2 + s;
        gB[s] = Bm + (size_t)(ctile * 128 + seg*16 + lr4) * 1024 + lcc;
        lB[s] = sB + seg * 512;
    }

    f32x4 acc[RT][4];
#pragma unroll
    for (int i = 0; i < RT; ++i)
#pragma unroll
        for (int j = 0; j < 4; ++j) acc[i][j] = (f32x4){0.f,0.f,0.f,0.f};

    const int c0 = (quad ^ ((ln >> 1) & 3)) * 8;

    // prologue: stage kt=0 -> buf0, kt=1 -> buf1
#pragma unroll
    for (int s = 0; s < RT/2; ++s) gl_lds16(gA[s], lA[s]);
#pragma unroll
    for (int s = 0; s < 2; ++s)    gl_lds16(gB[s], lB[s]);
#pragma unroll
    for (int s = 0; s < RT/2; ++s) gl_lds16(gA[s] + 32, lA[s] + ABUF);
#pragma unroll
    for (int s = 0; s < 2; ++s)    gl_lds16(gB[s] + 32, lB[s] + BBUF);

    int bc = 0, bp = 2;
    for (int kt = 0; kt < 32; ++kt) {
        if (RT == 4) wbar_vm4(); else wbar_vm3();   // drain kt's loads only
        int pk = (kt + 2) & 31;                     // wrap keeps waitcnt uniform
#pragma unroll
        for (int s = 0; s < RT/2; ++s) gl_lds16(gA[s] + pk*32, lA[s] + bp*ABUF);
#pragma unroll
        for (int s = 0; s < 2; ++s)    gl_lds16(gB[s] + pk*32, lB[s] + bp*BBUF);

        const u16* sAb = sA + bc * ABUF;
        const u16* sBb = sB + bc * BBUF;
        bf16x8 af[RT], bfr[4];
#pragma unroll
        for (int rt = 0; rt < RT; ++rt)
            af[rt] = *(const bf16x8*)(sAb + (wr*(RT*16) + rt*16 + ln) * 32 + c0);
#pragma unroll
        for (int ct = 0; ct < 4; ++ct)
            bfr[ct] = *(const bf16x8*)(sBb + (wc*64 + ct*16 + ln) * 32 + c0);
#pragma unroll
        for (int rt = 0; rt < RT; ++rt)
#pragma unroll
            for (int ct = 0; ct < 4; ++ct)
                acc[rt][ct] = __builtin_amdgcn_mfma_f32_16x16x32_bf16(
                    af[rt], bfr[ct], acc[rt][ct], 0, 0, 0);

        bc = (bc == 2) ? 0 : bc + 1;
        bp = (bp == 2) ? 0 : bp + 1;
    }
    vm_drain();   // in-flight gl_lds must not land after LDS is reallocated

#pragma unroll
    for (int rt = 0; rt < RT; ++rt) {
#pragma unroll
        for (int ct = 0; ct < 4; ++ct) {
#pragma unroll
            for (int i = 0; i < 4; ++i) {
                int R = rtile*(RT*32) + wr*(RT*16) + rt*16 + quad*4 + i;
                int C = ctile*128 + wc*64 + ct*16 + ln;
                float val = acc[rt][ct][i];
                if (mode == 0) {
                    int b = R >> 11, s = R & 2047, h = C >> 6, d = C & 63;
                    ((u16*)Y)[((size_t)((b*NH + h) * SEQ + s) << 6) + d] = f2bf(val);
                } else if (mode == 1) {
                    int h = R >> 6, d = R & 63, b = C >> 11, n = C & 2047;
                    ((u16*)Y)[((size_t)((b*NH + h) * 64 + d) << 11) + n] = f2bf(val);
                } else {
                    ((float*)Y)[(size_t)R * 1024 + C] = val;
                }
            }
        }
    }
}

struct QKVArgs { const u16* A[3]; const u16* B[3]; u16* Y[3]; };

__global__ __launch_bounds__(256) void gemm_qkv(QKVArgs g) {
    __shared__ u16 sA[3 * 128 * 32];
    __shared__ u16 sB[3 * 128 * 32];
    int z = blockIdx.z;
    if (z == 2)
        gemm_body<4>(g.A[2], g.B[2], g.Y[2], blockIdx.y, blockIdx.x, 1, sA, sB);
    else
        gemm_body<4>(g.A[z], g.B[z], g.Y[z], blockIdx.x, blockIdx.y, 0, sA, sB);
}

__global__ __launch_bounds__(256) void gemm_out(const u16* __restrict__ A,
                                                const u16* __restrict__ Bm,
                                                float* __restrict__ Y) {
    __shared__ u16 sA[3 * 64 * 32];
    __shared__ u16 sB[3 * 128 * 32];
    gemm_body<2>(A, Bm, Y, blockIdx.x, blockIdx.y, 2, sA, sB);
}

// ---------------------------------------------------------------------------
// Flash attention v7: in-register P (no P LDS slab at all).
// Key insight: PV's k-dim is a reduction over n -> any n-permutation is legal
// if the P-fragment and V-fragment use the SAME order. The QK S^T output
// already has A-row = ln at every lane; only the k-slot order differs from
// the standard A-layout. So the PV A-frag is built DIRECTLY from the cvt_pk
// outputs (sigma: slot q*8+j <-> n = j<4 ? q*4+j : 16+q*4+(j-4)), and V is
// read with two ds_read_b64 per fragment at the sigma-matched offsets
// (the 16B XOR staging swizzle makes these 2-way conflicts = free).
// Removes: P ds_writes, P ds_reads, the in-iter lgkm round-trip, 36KB LDS.
// LDS 48KB -> 3 blocks/CU = 24 waves/CU (launch_bounds(512,6) caps VGPR).
// Skeleton = v4: K/V 3-buf, prefetch dist 2, one raw barrier @ vmcnt(3).
// ---------------------------------------------------------------------------
__global__ __launch_bounds__(512, 6) void attn_kernel(
    const u16* __restrict__ qw,
    const u16* __restrict__ kw,
    const u16* __restrict__ vt,
    const u32* __restrict__ mbits,
    u16* __restrict__ ctx) {

    __shared__ u16 sK[3 * 4096];            // 24 KB
    __shared__ u16 sV[3 * 4096];            // 24 KB

    const int mtile = blockIdx.x;           // 0..15 (128 m-rows each)
    const int bh    = blockIdx.y;           // 0..31
    const int b     = bh >> 4;
    const int tid   = threadIdx.x;
    const int wv    = tid >> 6, lane = tid & 63;
    const int quad  = lane >> 4, ln = lane & 15;
    const int m0    = mtile * 128;

    const size_t hbase = (size_t)bh * SEQ * 64;

    // Q fragments (B operand of S^T): rows m = m0 + wv*16 + ln
    bf16x8 qf[2];
    {
        const u16* qp = qw + hbase + (size_t)(m0 + wv*16 + ln) * 64 + quad*8;
        qf[0] = *(const bf16x8*)(qp);
        qf[1] = *(const bf16x8*)(qp + 32);
    }

    f32x4 o[4], lsum;
    lsum = (f32x4){0.f,0.f,0.f,0.f};
#pragma unroll
    for (int j = 0; j < 4; ++j) o[j] = (f32x4){0.f,0.f,0.f,0.f};

    bf16x8 ones;
#pragma unroll
    for (int i = 0; i < 8; ++i) ones[i] = (short)0x3F80;   // bf16 1.0

    const u32* mrow = mbits + (size_t)(b*SEQ + m0 + wv*16 + ln) * 64;

    // K/V staging: one 16B shot per thread per tile (512 thr x 16B = 8KB)
    const int lr = lane >> 3;
    const int lc = (lane & 7) ^ lr;                      // XOR-swizzled chunk
    const u16* gK = kw + hbase + (size_t)(wv*8 + lr) * 64 + lc*8;
    const u16* gV = vt + hbase + (size_t)(wv*8 + lr) * SEQ + lc*8;
    u16* lK = sK + wv * 512;
    u16* lV = sV + wv * 512;

    const int c0 = (quad ^ (ln & 7)) * 8;                // K d-chunk (QK)

    // V read offsets (u16 units) for sigma-ordered b64 pairs.
    // logical 16B chunk c of row d sits at physical chunk c^(d&7); d&7 = ln&7.
    const int qh = quad >> 1, h4 = (quad & 1) * 4, sw = ln & 7;
    const int cA0 = ((qh    ) ^ sw) * 8 + h4;            // n = quad*4..+3
    const int cA1 = ((qh + 2) ^ sw) * 8 + h4;            // n = 16+quad*4..+3
    const int cB0 = ((qh + 4) ^ sw) * 8 + h4;            // n = 32+quad*4..+3
    const int cB1 = ((qh + 6) ^ sw) * 8 + h4;            // n = 48+quad*4..+3

    // prologue: tiles 0 and 1 -> bufs 0, 1 (order: K,V then mask, per tile)
    gl_lds16(gK, lK);
    gl_lds16(gV, lV);
    uint2 wwA = *(const uint2*)(mrow);
    gl_lds16(gK + 4096, lK + 4096);
    gl_lds16(gV + 64,   lV + 4096);
    uint2 wwB = *(const uint2*)(mrow + 2);

    int bc = 0, bp = 2;
    for (int nt = 0; nt < SEQ / 64; ++nt) {
        wbar_vm3();                          // drain tile nt's 3 loads only
        int pidx = (nt + 2) & 31;            // wrap keeps waitcnt uniform
        gl_lds16(gK + (size_t)pidx * 4096, lK + bp*4096);
        gl_lds16(gV + pidx * 64,           lV + bp*4096);
        uint2 wwC = *(const uint2*)(mrow + pidx*2);

        const u16* sKb = sK + bc * 4096;
        const u16* sVb = sV + bc * 4096;

        // S^T = K Q^T: D[row=quad*4+i -> n][col=ln -> m]
        f32x4 s4[4];
#pragma unroll
        for (int ct = 0; ct < 4; ++ct) {
            const u16* kp = sKb + (ct*16 + ln) * 64;
            bf16x8 k0 = *(const bf16x8*)(kp + c0);
            bf16x8 k1 = *(const bf16x8*)(kp + (c0 ^ 32));
            f32x4 z = (f32x4){0.f, 0.f, 0.f, 0.f};
            z = __builtin_amdgcn_mfma_f32_16x16x32_bf16(k0, qf[0], z, 0, 0, 0);
            z = __builtin_amdgcn_mfma_f32_16x16x32_bf16(k1, qf[1], z, 0, 0, 0);
            s4[ct] = z;
        }

        // p = exp2(s) & keep-mask -> packed bf16 P fragments, in registers.
        // pf0 covers n-tiles ct0,ct1 (sigma order); pf1 covers ct2,ct3.
        u32 P0[4], P1[4];
        {
            u32 l0 = ~(wwA.x >> (quad * 4));
            u32 l1 = ~(wwA.y >> (quad * 4));
#pragma unroll
            for (int ct = 0; ct < 4; ++ct) {
                u32 lsel = (ct & 2) ? l1 : l0;
                float p[4];
#pragma unroll
                for (int i = 0; i < 4; ++i)
                    p[i] = mask_exp2(s4[ct][i], lsel, (ct & 1) * 16 + i);
                u32 lo = pk2bf(p[0], p[1]);
                u32 hi = pk2bf(p[2], p[3]);
                if (ct == 0)      { P0[0] = lo; P0[1] = hi; }
                else if (ct == 1) { P0[2] = lo; P0[3] = hi; }
                else if (ct == 2) { P1[0] = lo; P1[1] = hi; }
                else              { P1[2] = lo; P1[3] = hi; }
            }
        }
        bf16x8 pf0, pf1;
        memcpy(&pf0, P0, 16);
        memcpy(&pf1, P1, 16);

        // O += P V ; lsum += P * ones  (V read in sigma order, 2x b64 each)
        lsum = __builtin_amdgcn_mfma_f32_16x16x32_bf16(pf0, ones, lsum, 0, 0, 0);
        lsum = __builtin_amdgcn_mfma_f32_16x16x32_bf16(pf1, ones, lsum, 0, 0, 0);
#pragma unroll
        for (int ct = 0; ct < 4; ++ct) {
            const u16* vrow = sVb + (ct*16 + ln) * 64;
            uint2 a0 = *(const uint2*)(vrow + cA0);
            uint2 a1 = *(const uint2*)(vrow + cA1);
            uint2 b0 = *(const uint2*)(vrow + cB0);
            uint2 b1 = *(const uint2*)(vrow + cB1);
            u32 V0[4] = {a0.x, a0.y, a1.x, a1.y};
            u32 V1[4] = {b0.x, b0.y, b1.x, b1.y};
            bf16x8 vf0, vf1;
            memcpy(&vf0, V0, 16);
            memcpy(&vf1, V1, 16);
            o[ct] = __builtin_amdgcn_mfma_f32_16x16x32_bf16(pf0, vf0, o[ct], 0, 0, 0);
            o[ct] = __builtin_amdgcn_mfma_f32_16x16x32_bf16(pf1, vf1, o[ct], 0, 0, 0);
        }

        wwA = wwB; wwB = wwC;
        bc = (bc == 2) ? 0 : bc + 1;
        bp = (bp == 2) ? 0 : bp + 1;
    }
    vm_drain();   // in-flight gl_lds must not land after LDS is reallocated

#pragma unroll
    for (int i = 0; i < 4; ++i) {
        float inv = 1.f / lsum[i];
        int m = m0 + wv*16 + quad*4 + i;
        size_t base = ((size_t)(b * SEQ + m) << 10) + (bh & 15) * 64;
#pragma unroll
        for (int ct = 0; ct < 4; ++ct)
            ctx[base + ct*16 + ln] = f2bf(o[ct][i] * inv);
    }
}

// ---------------------------------------------------------------------------
extern "C" void kernel_launch(void* const* d_in, const int* in_sizes, int n_in,
                              void* d_out, int out_size, void* d_ws, size_t ws_size,
                              hipStream_t stream) {
    const float* q    = (const float*)d_in[0];
    const float* k    = (const float*)d_in[1];
    const float* v    = (const float*)d_in[2];
    const int*   mask = (const int*)d_in[3];
    const float* Wq   = (const float*)d_in[4];
    const float* Wk   = (const float*)d_in[5];
    const float* Wv   = (const float*)d_in[6];
    const float* Wo   = (const float*)d_in[7];
    float* out = (float*)d_out;

    char* ws = (char*)d_ws;
    const size_t SZH = (size_t)NB * SEQ * DM * 2;       // 8 MiB
    const size_t SZW = (size_t)DM * DM * 2;             // 2 MiB
    u16* qw   = (u16*)(ws);
    u16* kw   = (u16*)(ws + SZH);
    u16* vt   = (u16*)(ws + 2*SZH);
    u16* ctx  = (u16*)(ws + 3*SZH);
    u16* vb   = ctx;                                    // v bf16 (dead before ctx)
    u32* mbits= (u32*)(ws + 4*SZH);                     // 1 MiB
    u16* qb   = (u16*)(ws + 4*SZH + (1u<<20));
    u16* kb   = (u16*)(ws + 4*SZH + (1u<<20) + SZH);
    u16* Wqb  = (u16*)(ws + 4*SZH + (1u<<20) + 2*SZH);
    u16* Wkb  = (u16*)((char*)Wqb + SZW);
    u16* Wvb  = (u16*)((char*)Wqb + 2*SZW);
    u16* Wob  = (u16*)((char*)Wqb + 3*SZW);

    const float CSC = 0.18033688011112042f;             // 0.125 * log2(e)

    CvtArgs ca;
    ca.s[0]=q;  ca.d[0]=qb;  ca.scale[0]=1.f;
    ca.s[1]=k;  ca.d[1]=kb;  ca.scale[1]=1.f;
    ca.s[2]=v;  ca.d[2]=vb;  ca.scale[2]=1.f;
    ca.s[3]=Wq; ca.d[3]=Wqb; ca.scale[3]=CSC;
    ca.s[4]=Wk; ca.d[4]=Wkb; ca.scale[4]=1.f;
    ca.s[5]=Wv; ca.d[5]=Wvb; ca.scale[5]=1.f;
    ca.s[6]=Wo; ca.d[6]=Wob; ca.scale[6]=1.f;
    int st[8] = {0, 2048, 4096, 6144, 6656, 7168, 7680, 8192};
    for (int i = 0; i < 8; ++i) ca.start[i] = st[i];
    cvt_kernel<<<dim3(8192), dim3(256), 0, stream>>>(ca);

    maskpack_kernel<<<dim3(NB*SEQ*SEQ/256), dim3(256), 0, stream>>>(mask, mbits);

    QKVArgs ga;
    ga.A[0]=qb;  ga.B[0]=Wqb; ga.Y[0]=qw;
    ga.A[1]=kb;  ga.B[1]=Wkb; ga.Y[1]=kw;
    ga.A[2]=Wvb; ga.B[2]=vb;  ga.Y[2]=vt;
    gemm_qkv<<<dim3(32, 8, 3), dim3(256), 0, stream>>>(ga);

    attn_kernel<<<dim3(SEQ/128, NB*NH), dim3(512), 0, stream>>>(qw, kw, vt, mbits, ctx);

    gemm_out<<<dim3(64, 8), dim3(256), 0, stream>>>(ctx, Wob, out);
}

// Round 5
// 257.880 us; speedup vs baseline: 1.0332x; 1.0332x over previous
//
#include <hip/hip_runtime.h>
#include <hip/hip_bf16.h>
#include <stdint.h>
#include <string.h>

// B=2, S=2048, D_MODEL=1024, H=16, Dh=64
#define SEQ   2048
#define DM    1024
#define NH    16
#define NB    2

typedef __attribute__((ext_vector_type(8))) short bf16x8;
typedef __attribute__((ext_vector_type(4))) float f32x4;
typedef unsigned short u16;
typedef unsigned int   u32;

__device__ __forceinline__ u16 f2bf(float f) {
    u32 u = __float_as_uint(f);
    u += 0x7FFF + ((u >> 16) & 1);   // RNE
    return (u16)(u >> 16);
}
__device__ __forceinline__ u32 pk2bf(float a, float b) {
    __hip_bfloat162 p = __float22bfloat162_rn(make_float2(a, b));
    u32 u; memcpy(&u, &p, 4); return u;
}
__device__ __forceinline__ float fexp2(float x) {
#if __has_builtin(__builtin_amdgcn_exp2f)
    return __builtin_amdgcn_exp2f(x);
#else
    return exp2f(x);
#endif
}
// exp2 with mask folded in: keep-bit (from inverted mask word) sign-extended
// and ANDed into the result. masked -> exactly 0.0f (== exp2(-1e9) path).
__device__ __forceinline__ float mask_exp2(float s, u32 lsel, int pos) {
#if __has_builtin(__builtin_amdgcn_sbfe)
    u32 keep = (u32)__builtin_amdgcn_sbfe((int)lsel, pos, 1);
#else
    u32 keep = (u32)((int)(lsel << (31 - pos)) >> 31);
#endif
    return __uint_as_float(__float_as_uint(fexp2(s)) & keep);
}
// async global->LDS, 16B/lane; LDS dest = wave-uniform base + lane*16
__device__ __forceinline__ void gl_lds16(const void* g, void* l) {
    __builtin_amdgcn_global_load_lds(
        (const __attribute__((address_space(1))) u32*)g,
        (__attribute__((address_space(3))) u32*)l, 16, 0, 0);
}
// Raw barrier WITHOUT vmcnt(0) drain: wait until only N newest VMEM ops
// remain in flight, then s_barrier. "memory" clobber pins ordering.
__device__ __forceinline__ void wbar_vm3() { asm volatile("s_waitcnt vmcnt(3)\ns_barrier" ::: "memory"); }
__device__ __forceinline__ void wbar_vm4() { asm volatile("s_waitcnt vmcnt(4)\ns_barrier" ::: "memory"); }
__device__ __forceinline__ void vm_drain() { asm volatile("s_waitcnt vmcnt(0)" ::: "memory"); }

// ---------------------------------------------------------------------------
// fp32 -> bf16 bulk convert; Wq pre-scaled by 0.125*log2(e) (exp2 domain).
// ---------------------------------------------------------------------------
struct CvtArgs {
    const float* s[7];
    u16* d[7];
    float scale[7];
    int start[8];
};
__global__ __launch_bounds__(256) void cvt_kernel(CvtArgs a) {
    int bid = blockIdx.x;
    int seg = 0;
#pragma unroll
    for (int i = 1; i < 7; ++i) if (bid >= a.start[i]) seg = i;
    float sc = a.scale[seg];
    size_t base = (size_t)(bid - a.start[seg]) * 2048 + threadIdx.x * 8;
    const float4* s4 = (const float4*)(a.s[seg] + base);
    float4 x = s4[0], y = s4[1];
    u32 r[4];
    r[0] = pk2bf(x.x*sc, x.y*sc); r[1] = pk2bf(x.z*sc, x.w*sc);
    r[2] = pk2bf(y.x*sc, y.y*sc); r[3] = pk2bf(y.z*sc, y.w*sc);
    *(uint4*)(a.d[seg] + base) = *(uint4*)r;
}

// ---------------------------------------------------------------------------
// mask -> bits; word = bits[(b*2048+m)*64 + n/32]
// ---------------------------------------------------------------------------
__global__ void maskpack_kernel(const int* __restrict__ mask,
                                unsigned int* __restrict__ bits) {
    int gid = blockIdx.x * 256 + threadIdx.x;
    int m = mask[gid];
    unsigned long long bal = __ballot(m != 0);
    int lane = threadIdx.x & 63;
    if (lane == 0)       bits[gid >> 5] = (u32)(bal & 0xFFFFFFFFull);
    else if (lane == 32) bits[gid >> 5] = (u32)(bal >> 32);
}

// ---------------------------------------------------------------------------
// bf16 GEMM: Y[r][c] = sum_k A[r][k]*B[c][k], K=1024, BK=32.
// Triple-buffered LDS, prefetch distance 2, raw-barrier pipeline (no vmcnt(0)
// drains inside the loop). XOR swizzle (4 chunks/row) for conflict-free b128.
// RT=4: 128x128 tile; RT=2: 64x128. 256 threads, waves 2x2.
// mode 0: bf16 (B,H,S,64); mode 1: bf16 (B,H,64,S) with sigma column perm
// (within each 64-col block) so attn's PV V-fragments are b128-contiguous;
// mode 2: fp32 row-major.
// ---------------------------------------------------------------------------
template<int RT>
__device__ __forceinline__ void gemm_body(const u16* __restrict__ A,
                                          const u16* __restrict__ Bm,
                                          void* __restrict__ Y,
                                          int rtile, int ctile, int mode,
                                          u16* sA, u16* sB) {
    constexpr int ABUF = RT * 32 * 32;          // u16 per A buffer
    constexpr int BBUF = 128 * 32;
    const int tid  = threadIdx.x;
    const int wv   = tid >> 6, lane = tid & 63;
    const int quad = lane >> 4, ln = lane & 15;
    const int wr   = wv >> 1,  wc  = wv & 1;

    const int lr4 = lane >> 2;                          // row in 16-row shot
    const int lcc = ((lane & 3) ^ ((lane >> 3) & 3)) * 8;  // swizzled src col

    const u16* gA[RT/2]; u16* lA[RT/2];
#pragma unroll
    for (int s = 0; s < RT/2; ++s) {
        int seg = wv * (RT/2) + s;
        gA[s] = A + (size_t)(rtile * (RT*32) + seg*16 + lr4) * 1024 + lcc;
        lA[s] = sA + seg * 512;
    }
    const u16* gB[2]; u16* lB[2];
#pragma unroll
    for (int s = 0; s < 2; ++s) {
        int seg = wv * 2 + s;
        gB[s] = Bm + (size_t)(ctile * 128 + seg*16 + lr4) * 1024 + lcc;
        lB[s] = sB + seg * 512;
    }

    f32x4 acc[RT][4];
#pragma unroll
    for (int i = 0; i < RT; ++i)
#pragma unroll
        for (int j = 0; j < 4; ++j) acc[i][j] = (f32x4){0.f,0.f,0.f,0.f};

    const int c0 = (quad ^ ((ln >> 1) & 3)) * 8;

    // prologue: stage kt=0 -> buf0, kt=1 -> buf1
#pragma unroll
    for (int s = 0; s < RT/2; ++s) gl_lds16(gA[s], lA[s]);
#pragma unroll
    for (int s = 0; s < 2; ++s)    gl_lds16(gB[s], lB[s]);
#pragma unroll
    for (int s = 0; s < RT/2; ++s) gl_lds16(gA[s] + 32, lA[s] + ABUF);
#pragma unroll
    for (int s = 0; s < 2; ++s)    gl_lds16(gB[s] + 32, lB[s] + BBUF);

    int bc = 0, bp = 2;
    for (int kt = 0; kt < 32; ++kt) {
        if (RT == 4) wbar_vm4(); else wbar_vm3();   // drain kt's loads only
        int pk = (kt + 2) & 31;                     // wrap keeps waitcnt uniform
#pragma unroll
        for (int s = 0; s < RT/2; ++s) gl_lds16(gA[s] + pk*32, lA[s] + bp*ABUF);
#pragma unroll
        for (int s = 0; s < 2; ++s)    gl_lds16(gB[s] + pk*32, lB[s] + bp*BBUF);

        const u16* sAb = sA + bc * ABUF;
        const u16* sBb = sB + bc * BBUF;
        bf16x8 af[RT], bfr[4];
#pragma unroll
        for (int rt = 0; rt < RT; ++rt)
            af[rt] = *(const bf16x8*)(sAb + (wr*(RT*16) + rt*16 + ln) * 32 + c0);
#pragma unroll
        for (int ct = 0; ct < 4; ++ct)
            bfr[ct] = *(const bf16x8*)(sBb + (wc*64 + ct*16 + ln) * 32 + c0);
#pragma unroll
        for (int rt = 0; rt < RT; ++rt)
#pragma unroll
            for (int ct = 0; ct < 4; ++ct)
                acc[rt][ct] = __builtin_amdgcn_mfma_f32_16x16x32_bf16(
                    af[rt], bfr[ct], acc[rt][ct], 0, 0, 0);

        bc = (bc == 2) ? 0 : bc + 1;
        bp = (bp == 2) ? 0 : bp + 1;
    }
    vm_drain();   // in-flight gl_lds must not land after LDS is reallocated

#pragma unroll
    for (int rt = 0; rt < RT; ++rt) {
#pragma unroll
        for (int ct = 0; ct < 4; ++ct) {
#pragma unroll
            for (int i = 0; i < 4; ++i) {
                int R = rtile*(RT*32) + wr*(RT*16) + rt*16 + quad*4 + i;
                int C = ctile*128 + wc*64 + ct*16 + ln;
                float val = acc[rt][ct][i];
                if (mode == 0) {
                    int b = R >> 11, s = R & 2047, h = C >> 6, d = C & 63;
                    ((u16*)Y)[((size_t)((b*NH + h) * SEQ + s) << 6) + d] = f2bf(val);
                } else if (mode == 1) {
                    int h = R >> 6, d = R & 63, b = C >> 11, n = C & 2047;
                    // sigma column perm within each 64-col block: position
                    // p = q*8+j holds n = (j<4 ? q*4+j : 16+q*4+j-4) (+32 hi)
                    int nl = n & 63;
                    int np = (nl & 32) | (((nl & 15) >> 2) << 3) | (nl & 3)
                           | ((nl & 16) >> 2);
                    n = (n & ~63) | np;
                    ((u16*)Y)[((size_t)((b*NH + h) * 64 + d) << 11) + n] = f2bf(val);
                } else {
                    ((float*)Y)[(size_t)R * 1024 + C] = val;
                }
            }
        }
    }
}

struct QKVArgs { const u16* A[3]; const u16* B[3]; u16* Y[3]; };

__global__ __launch_bounds__(256) void gemm_qkv(QKVArgs g) {
    __shared__ u16 sA[3 * 128 * 32];
    __shared__ u16 sB[3 * 128 * 32];
    int z = blockIdx.z;
    if (z == 2)
        gemm_body<4>(g.A[2], g.B[2], g.Y[2], blockIdx.y, blockIdx.x, 1, sA, sB);
    else
        gemm_body<4>(g.A[z], g.B[z], g.Y[z], blockIdx.x, blockIdx.y, 0, sA, sB);
}

__global__ __launch_bounds__(256) void gemm_out(const u16* __restrict__ A,
                                                const u16* __restrict__ Bm,
                                                float* __restrict__ Y) {
    __shared__ u16 sA[3 * 64 * 32];
    __shared__ u16 sB[3 * 128 * 32];
    gemm_body<2>(A, Bm, Y, blockIdx.x, blockIdx.y, 2, sA, sB);
}

// ---------------------------------------------------------------------------
// Flash attention v8 = v7 (in-register P) + producer-permuted V (b128 reads,
// same XOR pattern as K -> conflict-free) + 4-buffer unroll-4 K/V pipeline
// (compile-time buffer indices -> all ds_reads fold to 2 VGPR base addrs +
// immediate offsets) + s_setprio around MFMA clusters.
// v7 counters: 8.4M bank-conflict cycles (~18% of CU cycles) from the sigma
// b64 V reads; VGPR 40 (headroom); occupancy grid-capped at 2 blocks/CU so
// LDS 64KB is free. LDS: K 4x8KB | V 4x8KB = 64KB.
// Per-iter VMEM = {K,V,mask} prefetch at distance 2 -> raw barrier vmcnt(3).
// ---------------------------------------------------------------------------
__global__ __launch_bounds__(512, 4) void attn_kernel(
    const u16* __restrict__ qw,
    const u16* __restrict__ kw,
    const u16* __restrict__ vt,
    const u32* __restrict__ mbits,
    u16* __restrict__ ctx) {

    __shared__ __align__(16) u16 smem[32768];   // 64 KB: K bufs | V bufs
    u16* sK = smem;                              // bufs at bc*4096 (u16)
    u16* sV = smem + 16384;                      // byte 32768

    const int mtile = blockIdx.x;           // 0..15 (128 m-rows each)
    const int bh    = blockIdx.y;           // 0..31
    const int b     = bh >> 4;
    const int tid   = threadIdx.x;
    const int wv    = tid >> 6, lane = tid & 63;
    const int quad  = lane >> 4, ln = lane & 15;
    const int m0    = mtile * 128;

    const size_t hbase = (size_t)bh * SEQ * 64;

    // Q fragments (B operand of S^T): rows m = m0 + wv*16 + ln
    bf16x8 qf[2];
    {
        const u16* qp = qw + hbase + (size_t)(m0 + wv*16 + ln) * 64 + quad*8;
        qf[0] = *(const bf16x8*)(qp);
        qf[1] = *(const bf16x8*)(qp + 32);
    }

    f32x4 o[4], lsum;
    lsum = (f32x4){0.f,0.f,0.f,0.f};
#pragma unroll
    for (int j = 0; j < 4; ++j) o[j] = (f32x4){0.f,0.f,0.f,0.f};

    bf16x8 ones;
#pragma unroll
    for (int i = 0; i < 8; ++i) ones[i] = (short)0x3F80;   // bf16 1.0

    const u32* mrow = mbits + (size_t)(b*SEQ + m0 + wv*16 + ln) * 64;

    // K/V staging: one 16B shot per thread per tile (512 thr x 16B = 8KB)
    const int lr = lane >> 3;
    const int lc = (lane & 7) ^ lr;                      // XOR-swizzled chunk
    const u16* gK = kw + hbase + (size_t)(wv*8 + lr) * 64 + lc*8;
    const u16* gV = vt + hbase + (size_t)(wv*8 + lr) * SEQ + lc*8;
    u16* lK = sK + wv * 512;
    u16* lV = sV + wv * 512;

    // Two per-lane LDS base addresses serve ALL ds_reads (K and V) via
    // compile-time immediate offsets: row ln*64 u16, chunk c0 / c0^32.
    const int c0 = (quad ^ (ln & 7)) * 8;
    const u16* a1 = smem + ln*64 + c0;
    const u16* a2 = smem + ln*64 + (c0 ^ 32);

    // prologue: tiles 0 and 1 -> bufs 0, 1 (order: K,V then mask, per tile)
    gl_lds16(gK, lK);
    gl_lds16(gV, lV);
    uint2 wwA = *(const uint2*)(mrow);
    gl_lds16(gK + 4096, lK + 4096);
    gl_lds16(gV + 64,   lV + 4096);
    uint2 wwB = *(const uint2*)(mrow + 2);

    for (int mi = 0; mi < 8; ++mi) {
#pragma unroll
        for (int u = 0; u < 4; ++u) {
            const int bc = u;                 // read buf  = it & 3 = u
            const int wb = (u + 2) & 3;       // write buf = (it+2) & 3
            wbar_vm3();                       // drain tile it's 3 loads only
            int pidx = (mi*4 + u + 2) & 31;   // wrap keeps waitcnt uniform
            gl_lds16(gK + (size_t)pidx * 4096, lK + wb*4096);
            gl_lds16(gV + pidx * 64,           lV + wb*4096);
            uint2 wwC = *(const uint2*)(mrow + pidx*2);

            // S^T = K Q^T: D[row=quad*4+i -> n][col=ln -> m]
            f32x4 s4[4];
            __builtin_amdgcn_s_setprio(1);
#pragma unroll
            for (int ct = 0; ct < 4; ++ct) {
                bf16x8 k0 = *(const bf16x8*)(a1 + bc*4096 + ct*1024);
                bf16x8 k1 = *(const bf16x8*)(a2 + bc*4096 + ct*1024);
                f32x4 z = (f32x4){0.f, 0.f, 0.f, 0.f};
                z = __builtin_amdgcn_mfma_f32_16x16x32_bf16(k0, qf[0], z, 0, 0, 0);
                z = __builtin_amdgcn_mfma_f32_16x16x32_bf16(k1, qf[1], z, 0, 0, 0);
                s4[ct] = z;
            }
            __builtin_amdgcn_s_setprio(0);

            // p = exp2(s) & keep-mask -> packed bf16 P fragments in registers
            u32 P0[4], P1[4];
            {
                u32 l0 = ~(wwA.x >> (quad * 4));
                u32 l1 = ~(wwA.y >> (quad * 4));
#pragma unroll
                for (int ct = 0; ct < 4; ++ct) {
                    u32 lsel = (ct & 2) ? l1 : l0;
                    float p[4];
#pragma unroll
                    for (int i = 0; i < 4; ++i)
                        p[i] = mask_exp2(s4[ct][i], lsel, (ct & 1) * 16 + i);
                    u32 lo = pk2bf(p[0], p[1]);
                    u32 hi = pk2bf(p[2], p[3]);
                    if (ct == 0)      { P0[0] = lo; P0[1] = hi; }
                    else if (ct == 1) { P0[2] = lo; P0[3] = hi; }
                    else if (ct == 2) { P1[0] = lo; P1[1] = hi; }
                    else              { P1[2] = lo; P1[3] = hi; }
                }
            }
            bf16x8 pf0, pf1;
            memcpy(&pf0, P0, 16);
            memcpy(&pf1, P1, 16);

            // O += P V ; lsum += P * ones. V is producer-permuted: fragment
            // = one b128 at the SAME XOR pattern as K (chunk quad / quad^4).
            __builtin_amdgcn_s_setprio(1);
            lsum = __builtin_amdgcn_mfma_f32_16x16x32_bf16(pf0, ones, lsum, 0, 0, 0);
            lsum = __builtin_amdgcn_mfma_f32_16x16x32_bf16(pf1, ones, lsum, 0, 0, 0);
#pragma unroll
            for (int ct = 0; ct < 4; ++ct) {
                bf16x8 vf0 = *(const bf16x8*)(a1 + 16384 + bc*4096 + ct*1024);
                bf16x8 vf1 = *(const bf16x8*)(a2 + 16384 + bc*4096 + ct*1024);
                o[ct] = __builtin_amdgcn_mfma_f32_16x16x32_bf16(pf0, vf0, o[ct], 0, 0, 0);
                o[ct] = __builtin_amdgcn_mfma_f32_16x16x32_bf16(pf1, vf1, o[ct], 0, 0, 0);
            }
            __builtin_amdgcn_s_setprio(0);

            wwA = wwB; wwB = wwC;
        }
    }
    vm_drain();   // in-flight gl_lds must not land after LDS is reallocated

#pragma unroll
    for (int i = 0; i < 4; ++i) {
        float inv = 1.f / lsum[i];
        int m = m0 + wv*16 + quad*4 + i;
        size_t base = ((size_t)(b * SEQ + m) << 10) + (bh & 15) * 64;
#pragma unroll
        for (int ct = 0; ct < 4; ++ct)
            ctx[base + ct*16 + ln] = f2bf(o[ct][i] * inv);
    }
}

// ---------------------------------------------------------------------------
extern "C" void kernel_launch(void* const* d_in, const int* in_sizes, int n_in,
                              void* d_out, int out_size, void* d_ws, size_t ws_size,
                              hipStream_t stream) {
    const float* q    = (const float*)d_in[0];
    const float* k    = (const float*)d_in[1];
    const float* v    = (const float*)d_in[2];
    const int*   mask = (const int*)d_in[3];
    const float* Wq   = (const float*)d_in[4];
    const float* Wk   = (const float*)d_in[5];
    const float* Wv   = (const float*)d_in[6];
    const float* Wo   = (const float*)d_in[7];
    float* out = (float*)d_out;

    char* ws = (char*)d_ws;
    const size_t SZH = (size_t)NB * SEQ * DM * 2;       // 8 MiB
    const size_t SZW = (size_t)DM * DM * 2;             // 2 MiB
    u16* qw   = (u16*)(ws);
    u16* kw   = (u16*)(ws + SZH);
    u16* vt   = (u16*)(ws + 2*SZH);
    u16* ctx  = (u16*)(ws + 3*SZH);
    u16* vb   = ctx;                                    // v bf16 (dead before ctx)
    u32* mbits= (u32*)(ws + 4*SZH);                     // 1 MiB
    u16* qb   = (u16*)(ws + 4*SZH + (1u<<20));
    u16* kb   = (u16*)(ws + 4*SZH + (1u<<20) + SZH);
    u16* Wqb  = (u16*)(ws + 4*SZH + (1u<<20) + 2*SZH);
    u16* Wkb  = (u16*)((char*)Wqb + SZW);
    u16* Wvb  = (u16*)((char*)Wqb + 2*SZW);
    u16* Wob  = (u16*)((char*)Wqb + 3*SZW);

    const float CSC = 0.18033688011112042f;             // 0.125 * log2(e)

    CvtArgs ca;
    ca.s[0]=q;  ca.d[0]=qb;  ca.scale[0]=1.f;
    ca.s[1]=k;  ca.d[1]=kb;  ca.scale[1]=1.f;
    ca.s[2]=v;  ca.d[2]=vb;  ca.scale[2]=1.f;
    ca.s[3]=Wq; ca.d[3]=Wqb; ca.scale[3]=CSC;
    ca.s[4]=Wk; ca.d[4]=Wkb; ca.scale[4]=1.f;
    ca.s[5]=Wv; ca.d[5]=Wvb; ca.scale[5]=1.f;
    ca.s[6]=Wo; ca.d[6]=Wob; ca.scale[6]=1.f;
    int st[8] = {0, 2048, 4096, 6144, 6656, 7168, 7680, 8192};
    for (int i = 0; i < 8; ++i) ca.start[i] = st[i];
    cvt_kernel<<<dim3(8192), dim3(256), 0, stream>>>(ca);

    maskpack_kernel<<<dim3(NB*SEQ*SEQ/256), dim3(256), 0, stream>>>(mask, mbits);

    QKVArgs ga;
    ga.A[0]=qb;  ga.B[0]=Wqb; ga.Y[0]=qw;
    ga.A[1]=kb;  ga.B[1]=Wkb; ga.Y[1]=kw;
    ga.A[2]=Wvb; ga.B[2]=vb;  ga.Y[2]=vt;
    gemm_qkv<<<dim3(32, 8, 3), dim3(256), 0, stream>>>(ga);

    attn_kernel<<<dim3(SEQ/128, NB*NH), dim3(512), 0, stream>>>(qw, kw, vt, mbits, ctx);

    gemm_out<<<dim3(64, 8), dim3(256), 0, stream>>>(ctx, Wob, out);
}

// Round 6
// 242.800 us; speedup vs baseline: 1.0974x; 1.0621x over previous
//
#include <hip/hip_runtime.h>
#include <hip/hip_bf16.h>
#include <stdint.h>
#include <string.h>

// B=2, S=2048, D_MODEL=1024, H=16, Dh=64
#define SEQ   2048
#define DM    1024
#define NH    16
#define NB    2

typedef __attribute__((ext_vector_type(8))) short bf16x8;
typedef __attribute__((ext_vector_type(4))) float f32x4;
typedef unsigned short u16;
typedef unsigned int   u32;

__device__ __forceinline__ u16 f2bf(float f) {
    u32 u = __float_as_uint(f);
    u += 0x7FFF + ((u >> 16) & 1);   // RNE
    return (u16)(u >> 16);
}
__device__ __forceinline__ u32 pk2bf(float a, float b) {
    __hip_bfloat162 p = __float22bfloat162_rn(make_float2(a, b));
    u32 u; memcpy(&u, &p, 4); return u;
}
__device__ __forceinline__ float fexp2(float x) {
#if __has_builtin(__builtin_amdgcn_exp2f)
    return __builtin_amdgcn_exp2f(x);
#else
    return exp2f(x);
#endif
}
// exp2 with mask folded in: keep-bit (from inverted mask word) sign-extended
// and ANDed into the result. masked -> exactly 0.0f (== exp2(-1e9) path).
__device__ __forceinline__ float mask_exp2(float s, u32 lsel, int pos) {
#if __has_builtin(__builtin_amdgcn_sbfe)
    u32 keep = (u32)__builtin_amdgcn_sbfe((int)lsel, pos, 1);
#else
    u32 keep = (u32)((int)(lsel << (31 - pos)) >> 31);
#endif
    return __uint_as_float(__float_as_uint(fexp2(s)) & keep);
}
// async global->LDS, 16B/lane; LDS dest = wave-uniform base + lane*16
__device__ __forceinline__ void gl_lds16(const void* g, void* l) {
    __builtin_amdgcn_global_load_lds(
        (const __attribute__((address_space(1))) u32*)g,
        (__attribute__((address_space(3))) u32*)l, 16, 0, 0);
}
// Raw barrier WITHOUT vmcnt(0) drain: wait until only N newest VMEM ops
// remain in flight, then s_barrier. "memory" clobber pins ordering.
__device__ __forceinline__ void wbar_vm3() { asm volatile("s_waitcnt vmcnt(3)\ns_barrier" ::: "memory"); }
__device__ __forceinline__ void wbar_vm4() { asm volatile("s_waitcnt vmcnt(4)\ns_barrier" ::: "memory"); }
__device__ __forceinline__ void vm_drain() { asm volatile("s_waitcnt vmcnt(0)" ::: "memory"); }

// ---------------------------------------------------------------------------
// Merged fp32->bf16 convert + maskpack (one launch fewer).
// bid < 8192: bulk cvt; Wq pre-scaled by 0.125*log2(e) (exp2 domain).
// bid >= 8192: maskpack, 4 ints/thread via uint4 + 4x __ballot.
// Bit layout (ballot-native, consumed by attn): per 64-n tile one u64
// (uint2); halfword i holds bits for n%4==i, bit index = (n%64)>>2.
// ---------------------------------------------------------------------------
struct CvtArgs {
    const float* s[7];
    u16* d[7];
    float scale[7];
    int start[8];
    const int* mask;
    u32* mbits;
};
__global__ __launch_bounds__(256) void cvt_kernel(CvtArgs a) {
    int bid = blockIdx.x;
    int tid = threadIdx.x;
    if (bid >= 8192) {
        int widx = (bid - 8192) * 256 + tid;          // uint4 index
        uint4 v = ((const uint4*)a.mask)[widx];
        unsigned long long b0 = __ballot(v.x != 0);
        unsigned long long b1 = __ballot(v.y != 0);
        unsigned long long b2 = __ballot(v.z != 0);
        unsigned long long b3 = __ballot(v.w != 0);
        int lane = tid & 63;
        if (lane < 4) {
            int sh = lane * 16;
            u32 lo = (u32)((b0 >> sh) & 0xFFFF) | ((u32)((b1 >> sh) & 0xFFFF) << 16);
            u32 hi = (u32)((b2 >> sh) & 0xFFFF) | ((u32)((b3 >> sh) & 0xFFFF) << 16);
            size_t N = (size_t)(bid - 8192) * 1024 + (size_t)(tid >> 6) * 256
                     + (size_t)lane * 64;              // global element index
            u32* dst = a.mbits + ((N >> 11) * 64 + ((N >> 6) & 31) * 2);
            *(uint2*)dst = make_uint2(lo, hi);
        }
        return;
    }
    int seg = 0;
#pragma unroll
    for (int i = 1; i < 7; ++i) if (bid >= a.start[i]) seg = i;
    float sc = a.scale[seg];
    size_t base = (size_t)(bid - a.start[seg]) * 2048 + tid * 8;
    const float4* s4 = (const float4*)(a.s[seg] + base);
    float4 x = s4[0], y = s4[1];
    u32 r[4];
    r[0] = pk2bf(x.x*sc, x.y*sc); r[1] = pk2bf(x.z*sc, x.w*sc);
    r[2] = pk2bf(y.x*sc, y.y*sc); r[3] = pk2bf(y.z*sc, y.w*sc);
    *(uint4*)(a.d[seg] + base) = *(uint4*)r;
}

// ---------------------------------------------------------------------------
// bf16 GEMM: Y[r][c] = sum_k A[r][k]*B[c][k], K=1024, BK=32.
// Triple-buffered LDS, prefetch distance 2, raw-barrier pipeline (no vmcnt(0)
// drains inside the loop). XOR swizzle (4 chunks/row) for conflict-free b128.
// RT=4: 128x128 tile; RT=2: 64x128. 256 threads, waves 2x2.
// mode 0: bf16 (B,H,S,64); mode 1: bf16 (B,H,64,S) with sigma column perm
// (within each 64-col block) so attn's PV V-fragments are b128-contiguous;
// mode 2: fp32 row-major.
// ---------------------------------------------------------------------------
template<int RT>
__device__ __forceinline__ void gemm_body(const u16* __restrict__ A,
                                          const u16* __restrict__ Bm,
                                          void* __restrict__ Y,
                                          int rtile, int ctile, int mode,
                                          u16* sA, u16* sB) {
    constexpr int ABUF = RT * 32 * 32;          // u16 per A buffer
    constexpr int BBUF = 128 * 32;
    const int tid  = threadIdx.x;
    const int wv   = tid >> 6, lane = tid & 63;
    const int quad = lane >> 4, ln = lane & 15;
    const int wr   = wv >> 1,  wc  = wv & 1;

    const int lr4 = lane >> 2;                          // row in 16-row shot
    const int lcc = ((lane & 3) ^ ((lane >> 3) & 3)) * 8;  // swizzled src col

    const u16* gA[RT/2]; u16* lA[RT/2];
#pragma unroll
    for (int s = 0; s < RT/2; ++s) {
        int seg = wv * (RT/2) + s;
        gA[s] = A + (size_t)(rtile * (RT*32) + seg*16 + lr4) * 1024 + lcc;
        lA[s] = sA + seg * 512;
    }
    const u16* gB[2]; u16* lB[2];
#pragma unroll
    for (int s = 0; s < 2; ++s) {
        int seg = wv * 2 + s;
        gB[s] = Bm + (size_t)(ctile * 128 + seg*16 + lr4) * 1024 + lcc;
        lB[s] = sB + seg * 512;
    }

    f32x4 acc[RT][4];
#pragma unroll
    for (int i = 0; i < RT; ++i)
#pragma unroll
        for (int j = 0; j < 4; ++j) acc[i][j] = (f32x4){0.f,0.f,0.f,0.f};

    const int c0 = (quad ^ ((ln >> 1) & 3)) * 8;

    // prologue: stage kt=0 -> buf0, kt=1 -> buf1
#pragma unroll
    for (int s = 0; s < RT/2; ++s) gl_lds16(gA[s], lA[s]);
#pragma unroll
    for (int s = 0; s < 2; ++s)    gl_lds16(gB[s], lB[s]);
#pragma unroll
    for (int s = 0; s < RT/2; ++s) gl_lds16(gA[s] + 32, lA[s] + ABUF);
#pragma unroll
    for (int s = 0; s < 2; ++s)    gl_lds16(gB[s] + 32, lB[s] + BBUF);

    int bc = 0, bp = 2;
    for (int kt = 0; kt < 32; ++kt) {
        if (RT == 4) wbar_vm4(); else wbar_vm3();   // drain kt's loads only
        int pk = (kt + 2) & 31;                     // wrap keeps waitcnt uniform
#pragma unroll
        for (int s = 0; s < RT/2; ++s) gl_lds16(gA[s] + pk*32, lA[s] + bp*ABUF);
#pragma unroll
        for (int s = 0; s < 2; ++s)    gl_lds16(gB[s] + pk*32, lB[s] + bp*BBUF);

        const u16* sAb = sA + bc * ABUF;
        const u16* sBb = sB + bc * BBUF;
        bf16x8 af[RT], bfr[4];
#pragma unroll
        for (int rt = 0; rt < RT; ++rt)
            af[rt] = *(const bf16x8*)(sAb + (wr*(RT*16) + rt*16 + ln) * 32 + c0);
#pragma unroll
        for (int ct = 0; ct < 4; ++ct)
            bfr[ct] = *(const bf16x8*)(sBb + (wc*64 + ct*16 + ln) * 32 + c0);
#pragma unroll
        for (int rt = 0; rt < RT; ++rt)
#pragma unroll
            for (int ct = 0; ct < 4; ++ct)
                acc[rt][ct] = __builtin_amdgcn_mfma_f32_16x16x32_bf16(
                    af[rt], bfr[ct], acc[rt][ct], 0, 0, 0);

        bc = (bc == 2) ? 0 : bc + 1;
        bp = (bp == 2) ? 0 : bp + 1;
    }
    vm_drain();   // in-flight gl_lds must not land after LDS is reallocated

#pragma unroll
    for (int rt = 0; rt < RT; ++rt) {
#pragma unroll
        for (int ct = 0; ct < 4; ++ct) {
#pragma unroll
            for (int i = 0; i < 4; ++i) {
                int R = rtile*(RT*32) + wr*(RT*16) + rt*16 + quad*4 + i;
                int C = ctile*128 + wc*64 + ct*16 + ln;
                float val = acc[rt][ct][i];
                if (mode == 0) {
                    int b = R >> 11, s = R & 2047, h = C >> 6, d = C & 63;
                    ((u16*)Y)[((size_t)((b*NH + h) * SEQ + s) << 6) + d] = f2bf(val);
                } else if (mode == 1) {
                    int h = R >> 6, d = R & 63, b = C >> 11, n = C & 2047;
                    // sigma column perm within each 64-col block: position
                    // p = q*8+j holds n = (j<4 ? q*4+j : 16+q*4+j-4) (+32 hi)
                    int nl = n & 63;
                    int np = (nl & 32) | (((nl & 15) >> 2) << 3) | (nl & 3)
                           | ((nl & 16) >> 2);
                    n = (n & ~63) | np;
                    ((u16*)Y)[((size_t)((b*NH + h) * 64 + d) << 11) + n] = f2bf(val);
                } else {
                    ((float*)Y)[(size_t)R * 1024 + C] = val;
                }
            }
        }
    }
}

struct QKVArgs { const u16* A[3]; const u16* B[3]; u16* Y[3]; };

__global__ __launch_bounds__(256) void gemm_qkv(QKVArgs g) {
    __shared__ u16 sA[3 * 128 * 32];
    __shared__ u16 sB[3 * 128 * 32];
    int z = blockIdx.z;
    if (z == 2)
        gemm_body<4>(g.A[2], g.B[2], g.Y[2], blockIdx.y, blockIdx.x, 1, sA, sB);
    else
        gemm_body<4>(g.A[z], g.B[z], g.Y[z], blockIdx.x, blockIdx.y, 0, sA, sB);
}

__global__ __launch_bounds__(256) void gemm_out(const u16* __restrict__ A,
                                                const u16* __restrict__ Bm,
                                                float* __restrict__ Y) {
    __shared__ u16 sA[3 * 64 * 32];
    __shared__ u16 sB[3 * 128 * 32];
    gemm_body<2>(A, Bm, Y, blockIdx.x, blockIdx.y, 2, sA, sB);
}

// ---------------------------------------------------------------------------
// Flash attention v8 (67.2us, 0 bank conflicts): in-register P +
// producer-permuted V (b128 reads, same XOR pattern as K) + 4-buffer unroll-4
// K/V pipeline (compile-time buffer indices) + s_setprio on MFMA clusters.
// v9 delta: mask words now in ballot-native layout (halfword i of the tile's
// u64 = bits for n%4==i, bit index (n%64)>>2) -> decode cost unchanged,
// produced by the merged cvt+maskpack kernel.
// LDS: K 4x8KB | V 4x8KB = 64KB. Per-iter VMEM = {K,V,mask}, dist 2 ->
// raw barrier vmcnt(3).
// ---------------------------------------------------------------------------
__global__ __launch_bounds__(512, 4) void attn_kernel(
    const u16* __restrict__ qw,
    const u16* __restrict__ kw,
    const u16* __restrict__ vt,
    const u32* __restrict__ mbits,
    u16* __restrict__ ctx) {

    __shared__ __align__(16) u16 smem[32768];   // 64 KB: K bufs | V bufs
    u16* sK = smem;                              // bufs at bc*4096 (u16)
    u16* sV = smem + 16384;                      // byte 32768

    const int mtile = blockIdx.x;           // 0..15 (128 m-rows each)
    const int bh    = blockIdx.y;           // 0..31
    const int b     = bh >> 4;
    const int tid   = threadIdx.x;
    const int wv    = tid >> 6, lane = tid & 63;
    const int quad  = lane >> 4, ln = lane & 15;
    const int m0    = mtile * 128;

    const size_t hbase = (size_t)bh * SEQ * 64;

    // Q fragments (B operand of S^T): rows m = m0 + wv*16 + ln
    bf16x8 qf[2];
    {
        const u16* qp = qw + hbase + (size_t)(m0 + wv*16 + ln) * 64 + quad*8;
        qf[0] = *(const bf16x8*)(qp);
        qf[1] = *(const bf16x8*)(qp + 32);
    }

    f32x4 o[4], lsum;
    lsum = (f32x4){0.f,0.f,0.f,0.f};
#pragma unroll
    for (int j = 0; j < 4; ++j) o[j] = (f32x4){0.f,0.f,0.f,0.f};

    bf16x8 ones;
#pragma unroll
    for (int i = 0; i < 8; ++i) ones[i] = (short)0x3F80;   // bf16 1.0

    const u32* mrow = mbits + (size_t)(b*SEQ + m0 + wv*16 + ln) * 64;

    // K/V staging: one 16B shot per thread per tile (512 thr x 16B = 8KB)
    const int lr = lane >> 3;
    const int lc = (lane & 7) ^ lr;                      // XOR-swizzled chunk
    const u16* gK = kw + hbase + (size_t)(wv*8 + lr) * 64 + lc*8;
    const u16* gV = vt + hbase + (size_t)(wv*8 + lr) * SEQ + lc*8;
    u16* lK = sK + wv * 512;
    u16* lV = sV + wv * 512;

    // Two per-lane LDS base addresses serve ALL ds_reads (K and V) via
    // compile-time immediate offsets: row ln*64 u16, chunk c0 / c0^32.
    const int c0 = (quad ^ (ln & 7)) * 8;
    const u16* a1 = smem + ln*64 + c0;
    const u16* a2 = smem + ln*64 + (c0 ^ 32);

    // prologue: tiles 0 and 1 -> bufs 0, 1 (order: K,V then mask, per tile)
    gl_lds16(gK, lK);
    gl_lds16(gV, lV);
    uint2 wwA = *(const uint2*)(mrow);
    gl_lds16(gK + 4096, lK + 4096);
    gl_lds16(gV + 64,   lV + 4096);
    uint2 wwB = *(const uint2*)(mrow + 2);

    for (int mi = 0; mi < 8; ++mi) {
#pragma unroll
        for (int u = 0; u < 4; ++u) {
            const int bc = u;                 // read buf  = it & 3 = u
            const int wb = (u + 2) & 3;       // write buf = (it+2) & 3
            wbar_vm3();                       // drain tile it's 3 loads only
            int pidx = (mi*4 + u + 2) & 31;   // wrap keeps waitcnt uniform
            gl_lds16(gK + (size_t)pidx * 4096, lK + wb*4096);
            gl_lds16(gV + pidx * 64,           lV + wb*4096);
            uint2 wwC = *(const uint2*)(mrow + pidx*2);

            // S^T = K Q^T: D[row=quad*4+i -> n][col=ln -> m]
            f32x4 s4[4];
            __builtin_amdgcn_s_setprio(1);
#pragma unroll
            for (int ct = 0; ct < 4; ++ct) {
                bf16x8 k0 = *(const bf16x8*)(a1 + bc*4096 + ct*1024);
                bf16x8 k1 = *(const bf16x8*)(a2 + bc*4096 + ct*1024);
                f32x4 z = (f32x4){0.f, 0.f, 0.f, 0.f};
                z = __builtin_amdgcn_mfma_f32_16x16x32_bf16(k0, qf[0], z, 0, 0, 0);
                z = __builtin_amdgcn_mfma_f32_16x16x32_bf16(k1, qf[1], z, 0, 0, 0);
                s4[ct] = z;
            }
            __builtin_amdgcn_s_setprio(0);

            // p = exp2(s) & keep-mask -> packed bf16 P fragments in registers
            // ballot-native mask: keep(ct,i) = bit (i&1)*16 + ct*4 + quad of
            // wwA.x (i<2) / wwA.y (i>=2); quad folded into the pre-shift.
            u32 P0[4], P1[4];
            {
                u32 l0 = ~(wwA.x >> quad);
                u32 l1 = ~(wwA.y >> quad);
#pragma unroll
                for (int ct = 0; ct < 4; ++ct) {
                    float p[4];
                    p[0] = mask_exp2(s4[ct][0], l0, ct*4);
                    p[1] = mask_exp2(s4[ct][1], l0, 16 + ct*4);
                    p[2] = mask_exp2(s4[ct][2], l1, ct*4);
                    p[3] = mask_exp2(s4[ct][3], l1, 16 + ct*4);
                    u32 lo = pk2bf(p[0], p[1]);
                    u32 hi = pk2bf(p[2], p[3]);
                    if (ct == 0)      { P0[0] = lo; P0[1] = hi; }
                    else if (ct == 1) { P0[2] = lo; P0[3] = hi; }
                    else if (ct == 2) { P1[0] = lo; P1[1] = hi; }
                    else              { P1[2] = lo; P1[3] = hi; }
                }
            }
            bf16x8 pf0, pf1;
            memcpy(&pf0, P0, 16);
            memcpy(&pf1, P1, 16);

            // O += P V ; lsum += P * ones. V is producer-permuted: fragment
            // = one b128 at the SAME XOR pattern as K (chunk quad / quad^4).
            __builtin_amdgcn_s_setprio(1);
            lsum = __builtin_amdgcn_mfma_f32_16x16x32_bf16(pf0, ones, lsum, 0, 0, 0);
            lsum = __builtin_amdgcn_mfma_f32_16x16x32_bf16(pf1, ones, lsum, 0, 0, 0);
#pragma unroll
            for (int ct = 0; ct < 4; ++ct) {
                bf16x8 vf0 = *(const bf16x8*)(a1 + 16384 + bc*4096 + ct*1024);
                bf16x8 vf1 = *(const bf16x8*)(a2 + 16384 + bc*4096 + ct*1024);
                o[ct] = __builtin_amdgcn_mfma_f32_16x16x32_bf16(pf0, vf0, o[ct], 0, 0, 0);
                o[ct] = __builtin_amdgcn_mfma_f32_16x16x32_bf16(pf1, vf1, o[ct], 0, 0, 0);
            }
            __builtin_amdgcn_s_setprio(0);

            wwA = wwB; wwB = wwC;
        }
    }
    vm_drain();   // in-flight gl_lds must not land after LDS is reallocated

#pragma unroll
    for (int i = 0; i < 4; ++i) {
        float inv = 1.f / lsum[i];
        int m = m0 + wv*16 + quad*4 + i;
        size_t base = ((size_t)(b * SEQ + m) << 10) + (bh & 15) * 64;
#pragma unroll
        for (int ct = 0; ct < 4; ++ct)
            ctx[base + ct*16 + ln] = f2bf(o[ct][i] * inv);
    }
}

// ---------------------------------------------------------------------------
extern "C" void kernel_launch(void* const* d_in, const int* in_sizes, int n_in,
                              void* d_out, int out_size, void* d_ws, size_t ws_size,
                              hipStream_t stream) {
    const float* q    = (const float*)d_in[0];
    const float* k    = (const float*)d_in[1];
    const float* v    = (const float*)d_in[2];
    const int*   mask = (const int*)d_in[3];
    const float* Wq   = (const float*)d_in[4];
    const float* Wk   = (const float*)d_in[5];
    const float* Wv   = (const float*)d_in[6];
    const float* Wo   = (const float*)d_in[7];
    float* out = (float*)d_out;

    char* ws = (char*)d_ws;
    const size_t SZH = (size_t)NB * SEQ * DM * 2;       // 8 MiB
    const size_t SZW = (size_t)DM * DM * 2;             // 2 MiB
    u16* qw   = (u16*)(ws);
    u16* kw   = (u16*)(ws + SZH);
    u16* vt   = (u16*)(ws + 2*SZH);
    u16* ctx  = (u16*)(ws + 3*SZH);
    u16* vb   = ctx;                                    // v bf16 (dead before ctx)
    u32* mbits= (u32*)(ws + 4*SZH);                     // 1 MiB
    u16* qb   = (u16*)(ws + 4*SZH + (1u<<20));
    u16* kb   = (u16*)(ws + 4*SZH + (1u<<20) + SZH);
    u16* Wqb  = (u16*)(ws + 4*SZH + (1u<<20) + 2*SZH);
    u16* Wkb  = (u16*)((char*)Wqb + SZW);
    u16* Wvb  = (u16*)((char*)Wqb + 2*SZW);
    u16* Wob  = (u16*)((char*)Wqb + 3*SZW);

    const float CSC = 0.18033688011112042f;             // 0.125 * log2(e)

    CvtArgs ca;
    ca.s[0]=q;  ca.d[0]=qb;  ca.scale[0]=1.f;
    ca.s[1]=k;  ca.d[1]=kb;  ca.scale[1]=1.f;
    ca.s[2]=v;  ca.d[2]=vb;  ca.scale[2]=1.f;
    ca.s[3]=Wq; ca.d[3]=Wqb; ca.scale[3]=CSC;
    ca.s[4]=Wk; ca.d[4]=Wkb; ca.scale[4]=1.f;
    ca.s[5]=Wv; ca.d[5]=Wvb; ca.scale[5]=1.f;
    ca.s[6]=Wo; ca.d[6]=Wob; ca.scale[6]=1.f;
    int st[8] = {0, 2048, 4096, 6144, 6656, 7168, 7680, 8192};
    for (int i = 0; i < 8; ++i) ca.start[i] = st[i];
    ca.mask  = mask;
    ca.mbits = mbits;
    // merged cvt (bid<8192) + maskpack (bid>=8192, 4 ints/thread)
    cvt_kernel<<<dim3(16384), dim3(256), 0, stream>>>(ca);

    QKVArgs ga;
    ga.A[0]=qb;  ga.B[0]=Wqb; ga.Y[0]=qw;
    ga.A[1]=kb;  ga.B[1]=Wkb; ga.Y[1]=kw;
    ga.A[2]=Wvb; ga.B[2]=vb;  ga.Y[2]=vt;
    gemm_qkv<<<dim3(32, 8, 3), dim3(256), 0, stream>>>(ga);

    attn_kernel<<<dim3(SEQ/128, NB*NH), dim3(512), 0, stream>>>(qw, kw, vt, mbits, ctx);

    gemm_out<<<dim3(64, 8), dim3(256), 0, stream>>>(ctx, Wob, out);
}